// Round 11
// baseline (312.494 us; speedup 1.0000x reference)
//
#include <hip/hip_runtime.h>
#include <hip/hip_bf16.h>

#define NN 100000
#define EE 1200000
#define HH 64
#define CC 10
#define GG 1000
#define NB_BUCKET 782          // ceil(NN/128)
#define BCAP 3072              // bucket capacity (mean 1536)
#define NSLICE 64              // stats atomic slices
#define GB 1563                // (NN+63)/64 gemm tiles

typedef unsigned int uint;
typedef unsigned short ushort;
typedef __attribute__((ext_vector_type(8))) short short8;   // 8 bf16 (4 VGPRs)
typedef __attribute__((ext_vector_type(4))) float f32x4;

// ---------- helpers ----------

__device__ __forceinline__ float b2fu(ushort u) {
    uint w = ((uint)u) << 16;
    float f; __builtin_memcpy(&f, &w, 4); return f;
}
__device__ __forceinline__ uint fbits(float f) { uint w; __builtin_memcpy(&w, &f, 4); return w; }
__device__ __forceinline__ float bitsf(uint w) { float f; __builtin_memcpy(&f, &w, 4); return f; }
__device__ __forceinline__ ushort f2b(float f) {
    uint w = fbits(f);
    w += 0x7FFFu + ((w >> 16) & 1u);
    return (ushort)(w >> 16);
}
__device__ __forceinline__ uint f2b2(float lo, float hi) {
    uint a = fbits(lo), b = fbits(hi);
    a += 0x7FFFu + ((a >> 16) & 1u);
    b += 0x7FFFu + ((b >> 16) & 1u);
    return (a >> 16) | (b & 0xFFFF0000u);
}
__device__ __forceinline__ float ldin(const void* p, int i, int bf) {
    if (bf) return b2fu(((const ushort*)p)[i]);
    return ((const float*)p)[i];
}
__device__ __forceinline__ void stout(void* p, int i, float v, int bf) {
    if (bf) ((ushort*)p)[i] = f2b(v);
    else    ((float*)p)[i] = v;
}
__device__ __forceinline__ short8 pack8(const float* v) {
    uint4 u;
    u.x = f2b2(v[0], v[1]); u.y = f2b2(v[2], v[3]);
    u.z = f2b2(v[4], v[5]); u.w = f2b2(v[6], v[7]);
    short8 r; __builtin_memcpy(&r, &u, 16); return r;
}

// unpack a uint4 (8 bf16) and fma into 8 named accumulators
#define ACCUM8(p0,p1,p2,p3,p4,p5,p6,p7, LU, WV) \
    p0 = fmaf(bitsf((LU).x << 16),          (WV), p0); \
    p1 = fmaf(bitsf((LU).x & 0xFFFF0000u),  (WV), p1); \
    p2 = fmaf(bitsf((LU).y << 16),          (WV), p2); \
    p3 = fmaf(bitsf((LU).y & 0xFFFF0000u),  (WV), p3); \
    p4 = fmaf(bitsf((LU).z << 16),          (WV), p4); \
    p5 = fmaf(bitsf((LU).z & 0xFFFF0000u),  (WV), p5); \
    p6 = fmaf(bitsf((LU).w << 16),          (WV), p6); \
    p7 = fmaf(bitsf((LU).w & 0xFFFF0000u),  (WV), p7);

// ---------------- prep: detect flag + zero bcur/stats + pre-pack W fragments ----------------
// W pack layout per matrix: 512 x uint4, index (t*2+q)*64 + l.

__global__ __launch_bounds__(256) void k_prep(const uint* __restrict__ x,
                                              const void* __restrict__ W0,
                                              const void* __restrict__ W1,
                                              const void* __restrict__ W2,
                                              int* __restrict__ flag,
                                              uint4* __restrict__ wpack,
                                              uint4* __restrict__ zp, int zq) {
    __shared__ int c2[2];
    __shared__ int cnt;
    int b = blockIdx.x, tid = threadIdx.x;
    if (b == 0) {
        if (tid == 0) cnt = 0;
        __syncthreads();
        if (tid < 128) {
            uint v = x[tid];
            int e = (v >> 7) & 0xFF;
            if (e >= 100 && e <= 133) atomicAdd(&cnt, 1);
        }
        __syncthreads();
        if (tid == 0) *flag = (cnt >= 96) ? 1 : 0;
    } else if (b <= 3) {
        // local bf16 detect (no cross-block dependency on flag)
        if (tid < 128) {
            uint v = x[tid];
            int e = (v >> 7) & 0xFF;
            unsigned long long m = __ballot(e >= 100 && e <= 133);
            if ((tid & 63) == 0) c2[tid >> 6] = (int)__popcll(m);
        }
        __syncthreads();
        int bf = (c2[0] + c2[1]) >= 96;
        const void* Wp = (b == 1) ? W0 : (b == 2) ? W1 : W2;
        uint4* wdst = wpack + (b - 1) * 512;
        for (int slot = tid; slot < 512; slot += 256) {
            int l = slot & 63, q = (slot >> 6) & 1, t = slot >> 7;
            int quad = l >> 4, n = l & 15;
            int ks = q * 32 + quad * 8;
            int col = t * 16 + n;
            float wv[8];
            #pragma unroll
            for (int j = 0; j < 8; ++j) wv[j] = ldin(Wp, (ks + j) * 64 + col, bf);
            uint4 u;
            u.x = f2b2(wv[0], wv[1]); u.y = f2b2(wv[2], wv[3]);
            u.z = f2b2(wv[4], wv[5]); u.w = f2b2(wv[6], wv[7]);
            wdst[(t * 2 + q) * 64 + l] = u;
        }
    } else {
        uint4 z4 = {0u, 0u, 0u, 0u};
        for (int i = (b - 4) * 256 + tid; i < zq; i += ((int)gridDim.x - 4) * 256)
            zp[i] = z4;
    }
}

// ---------------- edge scatter (stand-alone, 512 threads: proven config) ----------------

__global__ __launch_bounds__(512) void k_bscatter(const int* __restrict__ src,
                                                  const int* __restrict__ dst,
                                                  int* __restrict__ bcur,
                                                  uint* __restrict__ ebuf) {
    __shared__ int hist[NB_BUCKET];
    __shared__ int base[NB_BUCKET];
    int tid = threadIdx.x;
    const int chunk = (EE + gridDim.x - 1) / gridDim.x;
    int e0 = blockIdx.x * chunk;
    int e1 = e0 + chunk; if (e1 > EE) e1 = EE;
    for (int i = tid; i < NB_BUCKET; i += 512) hist[i] = 0;
    __syncthreads();
    for (int e = e0 + tid; e < e1; e += 512)
        atomicAdd(&hist[dst[e] >> 7], 1);
    __syncthreads();
    for (int b = tid; b < NB_BUCKET; b += 512) {
        int c = hist[b];
        base[b] = c ? (b * BCAP + atomicAdd(&bcur[b], c)) : 0;
        hist[b] = 0;
    }
    __syncthreads();
    for (int e = e0 + tid; e < e1; e += 512) {
        int d = dst[e];
        int b = d >> 7;
        int r = atomicAdd(&hist[b], 1);
        ebuf[base[b] + r] = (uint)src[e] | (((uint)d & 127u) << 17);
    }
}

// ---------------- shared-memory layouts ----------------

struct GemmSh {
    ushort Ct[64][64];           // epilogue transpose (8KB); aliased as f32 staging in MODE1 prologue
    float scA[64], shA[64];
};
struct BsortSh {
    int hist[128], sc[128], cur[128];
    int s_src[BCAP];
};
union BgU { GemmSh g; BsortSh b; };

// ---------------- bucket counting sort (256-thread variant, fused into bg0) ----------------

__device__ __forceinline__ void dev_bsort(const uint* __restrict__ ebuf,
                                          const int* __restrict__ bcur,
                                          uint* __restrict__ rowinfo,
                                          float* __restrict__ dis,
                                          int* __restrict__ csr,
                                          BsortSh& sh, int b) {
    int tid = threadIdx.x;
    int n0 = b << 7;
    int ebase = b * BCAP;
    int ecnt = bcur[b];
    if (ecnt > BCAP) ecnt = BCAP;
    if (tid < 128) sh.hist[tid] = 0;
    __syncthreads();
    for (int i = tid; i < ecnt; i += 256)
        atomicAdd(&sh.hist[ebuf[ebase + i] >> 17], 1);
    __syncthreads();
    if (tid < 128) sh.sc[tid] = sh.hist[tid];
    __syncthreads();
    for (int off = 1; off < 128; off <<= 1) {
        int t = (tid < 128 && tid >= off) ? sh.sc[tid - off] : 0;
        __syncthreads();
        if (tid < 128) sh.sc[tid] += t;
        __syncthreads();
    }
    if (tid < 128) {
        int excl = sh.sc[tid] - sh.hist[tid];
        sh.cur[tid] = excl;
        int node = n0 + tid;
        if (node < NN) {
            int dcap = sh.hist[tid] > 64 ? 64 : sh.hist[tid];
            rowinfo[node] = (uint)(ebase + excl) | ((uint)dcap << 22);
            dis[node] = rsqrtf((float)sh.hist[tid] + 1.0f);
        }
    }
    __syncthreads();
    for (int i = tid; i < ecnt; i += 256) {
        uint ed = ebuf[ebase + i];
        int p = atomicAdd(&sh.cur[ed >> 17], 1);
        sh.s_src[p] = (int)(ed & 0x1FFFFu);
    }
    __syncthreads();
    for (int i = tid; i < ecnt; i += 256)
        csr[ebase + i] = sh.s_src[i];
}

// ------- MFMA GEMM body. MODE 0: raw xw (NO dis scale; layer-0 agg applies it).
//         MODE 1: BN+ReLU on A, dis-scaled output. B-frags read directly from wpack (L2).
//         MODE 1 stats reduce: NSLICE/4 loads/thread across 256 threads + LDS combine. -------

template<int MODE>
__device__ __forceinline__ void dev_gemm(const void* __restrict__ A,
                                         const uint4* __restrict__ wp,
                                         const float* __restrict__ stats,
                                         const void* __restrict__ gam,
                                         const void* __restrict__ bet,
                                         const float* __restrict__ dis,
                                         ushort* __restrict__ outb,
                                         const int* __restrict__ flag,
                                         GemmSh& sh, int bx) {
    int bf = *flag;
    int tid = threadIdx.x;
    int row0 = bx * 64;

    if (MODE == 1) {
        float* stg = (float*)sh.Ct;              // 512 f32 staging (Ct reused later)
        int f = tid & 63, grp = tid >> 6;
        float se = 0.f, sq = 0.f;
        #pragma unroll
        for (int k = 0; k < NSLICE / 4; ++k) {
            int sl = grp * (NSLICE / 4) + k;
            se += stats[sl * 128 + f];
            sq += stats[sl * 128 + 64 + f];
        }
        stg[grp * 64 + f] = se;
        stg[256 + grp * 64 + f] = sq;
        __syncthreads();
        if (tid < 64) {
            float se4 = stg[tid] + stg[64 + tid] + stg[128 + tid] + stg[192 + tid];
            float sq4 = stg[256 + tid] + stg[320 + tid] + stg[384 + tid] + stg[448 + tid];
            float m = se4 * (1.0f / NN);
            float v = sq4 * (1.0f / NN) - m * m;
            float s = rsqrtf(v + 1e-5f) * ldin(gam, tid, bf);
            sh.scA[tid] = s;
            sh.shA[tid] = ldin(bet, tid, bf) - m * s;
        }
        __syncthreads();
    }

    int w = tid >> 6, lane = tid & 63;
    int quad = lane >> 4, mrow = lane & 15;
    int grow = row0 + w * 16 + mrow;
    int arow = (grow < NN) ? grow : 0;

    short8 a0, a1;
    if (MODE == 0) {
        if (bf) {
            const uint4* ap = (const uint4*)((const ushort*)A + (size_t)arow * 64);
            uint4 u0 = ap[quad], u1 = ap[4 + quad];
            __builtin_memcpy(&a0, &u0, 16);
            __builtin_memcpy(&a1, &u1, 16);
        } else {
            const float4* ap = (const float4*)((const float*)A + (size_t)arow * 64);
            float4 f0 = ap[quad * 2], f1 = ap[quad * 2 + 1];
            float4 f2 = ap[8 + quad * 2], f3 = ap[9 + quad * 2];
            float v0[8] = {f0.x, f0.y, f0.z, f0.w, f1.x, f1.y, f1.z, f1.w};
            float v1[8] = {f2.x, f2.y, f2.z, f2.w, f3.x, f3.y, f3.z, f3.w};
            a0 = pack8(v0);
            a1 = pack8(v1);
        }
    } else {
        const uint4* ap = (const uint4*)((const ushort*)A + (size_t)arow * 64);
        uint4 u0 = ap[quad], u1 = ap[4 + quad];
        const float4* sc4 = (const float4*)sh.scA;
        const float4* sh4 = (const float4*)sh.shA;
        float4 sa = sc4[quad * 2],     sb2 = sc4[quad * 2 + 1];
        float4 ha = sh4[quad * 2],     hb = sh4[quad * 2 + 1];
        float4 sa1 = sc4[8 + quad * 2], sb1 = sc4[9 + quad * 2];
        float4 ha1 = sh4[8 + quad * 2], hb1 = sh4[9 + quad * 2];
        float v0[8], v1[8];
        v0[0]=bitsf(u0.x<<16); v0[1]=bitsf(u0.x&0xFFFF0000u);
        v0[2]=bitsf(u0.y<<16); v0[3]=bitsf(u0.y&0xFFFF0000u);
        v0[4]=bitsf(u0.z<<16); v0[5]=bitsf(u0.z&0xFFFF0000u);
        v0[6]=bitsf(u0.w<<16); v0[7]=bitsf(u0.w&0xFFFF0000u);
        v1[0]=bitsf(u1.x<<16); v1[1]=bitsf(u1.x&0xFFFF0000u);
        v1[2]=bitsf(u1.y<<16); v1[3]=bitsf(u1.y&0xFFFF0000u);
        v1[4]=bitsf(u1.z<<16); v1[5]=bitsf(u1.z&0xFFFF0000u);
        v1[6]=bitsf(u1.w<<16); v1[7]=bitsf(u1.w&0xFFFF0000u);
        v0[0]=fmaxf(fmaf(v0[0],sa.x,ha.x),0.f); v0[1]=fmaxf(fmaf(v0[1],sa.y,ha.y),0.f);
        v0[2]=fmaxf(fmaf(v0[2],sa.z,ha.z),0.f); v0[3]=fmaxf(fmaf(v0[3],sa.w,ha.w),0.f);
        v0[4]=fmaxf(fmaf(v0[4],sb2.x,hb.x),0.f); v0[5]=fmaxf(fmaf(v0[5],sb2.y,hb.y),0.f);
        v0[6]=fmaxf(fmaf(v0[6],sb2.z,hb.z),0.f); v0[7]=fmaxf(fmaf(v0[7],sb2.w,hb.w),0.f);
        v1[0]=fmaxf(fmaf(v1[0],sa1.x,ha1.x),0.f); v1[1]=fmaxf(fmaf(v1[1],sa1.y,ha1.y),0.f);
        v1[2]=fmaxf(fmaf(v1[2],sa1.z,ha1.z),0.f); v1[3]=fmaxf(fmaf(v1[3],sa1.w,ha1.w),0.f);
        v1[4]=fmaxf(fmaf(v1[4],sb1.x,hb1.x),0.f); v1[5]=fmaxf(fmaf(v1[5],sb1.y,hb1.y),0.f);
        v1[6]=fmaxf(fmaf(v1[6],sb1.z,hb1.z),0.f); v1[7]=fmaxf(fmaf(v1[7],sb1.w,hb1.w),0.f);
        a0 = pack8(v0);
        a1 = pack8(v1);
    }

    f32x4 acc[4];
    #pragma unroll
    for (int t = 0; t < 4; ++t) {
        short8 b0, b1;
        uint4 ub0 = wp[(t * 2) * 64 + lane], ub1 = wp[(t * 2 + 1) * 64 + lane];
        __builtin_memcpy(&b0, &ub0, 16);
        __builtin_memcpy(&b1, &ub1, 16);
        f32x4 z = {0.f, 0.f, 0.f, 0.f};
        f32x4 c = __builtin_amdgcn_mfma_f32_16x16x32_bf16(a0, b0, z, 0, 0, 0);
        acc[t] = __builtin_amdgcn_mfma_f32_16x16x32_bf16(a1, b1, c, 0, 0, 0);
    }

    float dd[4];
    #pragma unroll
    for (int r = 0; r < 4; ++r) {
        if (MODE == 1) {
            int gr = row0 + w * 16 + quad * 4 + r;
            dd[r] = (gr < NN) ? dis[gr] : 0.f;
        } else dd[r] = 1.f;
    }
    #pragma unroll
    for (int t = 0; t < 4; ++t)
        #pragma unroll
        for (int r = 0; r < 4; ++r)
            sh.Ct[w * 16 + quad * 4 + r][t * 16 + mrow] = f2b(acc[t][r] * dd[r]);
    __syncthreads();

    int orow = tid >> 2, oc = (tid & 3) * 16;
    int growo = row0 + orow;
    if (growo < NN) {
        const uint4* lp = (const uint4*)&sh.Ct[orow][oc];
        uint4 q0 = lp[0], q1 = lp[1];
        uint4* op = (uint4*)(outb + (size_t)growo * 64 + oc);
        op[0] = q0; op[1] = q1;
    }
}

// fused: bucket sort (blocks [0,NB_BUCKET)) || layer-0 GEMM (blocks [NB_BUCKET, NB_BUCKET+GB))
__global__ __launch_bounds__(256) void k_bg0(const void* __restrict__ A,
                                             const uint4* __restrict__ wpack,
                                             ushort* __restrict__ xws,
                                             const int* __restrict__ flag,
                                             const uint* __restrict__ ebuf,
                                             const int* __restrict__ bcur,
                                             uint* __restrict__ rowinfo,
                                             float* __restrict__ dis,
                                             int* __restrict__ csr) {
    __shared__ BgU sh;
    int bx = blockIdx.x;
    if (bx < NB_BUCKET)
        dev_bsort(ebuf, bcur, rowinfo, dis, csr, sh.b, bx);
    else
        dev_gemm<0>(A, wpack, nullptr, nullptr, nullptr, nullptr, xws, flag, sh.g, bx - NB_BUCKET);
}

__global__ __launch_bounds__(256) void k_gemm1(const void* __restrict__ A,
                                               const uint4* __restrict__ wp,
                                               const float* __restrict__ stats,
                                               const void* __restrict__ gam,
                                               const void* __restrict__ bet,
                                               const float* __restrict__ dis,
                                               ushort* __restrict__ outb,
                                               const int* __restrict__ flag) {
    __shared__ GemmSh sh;
    dev_gemm<1>(A, wp, stats, gam, bet, dis, outb, flag, sh, blockIdx.x);
}

// ------- aggregate + fused BN stats — TWO nodes per wave, EIGHT rows per gather.
// lane = rg*8 + fb: fb in [0,8) = 8-feature block (16B, uint4), rg in [0,8) = row
// subgroup. One global_load_dwordx4 fetches 8 rows x 128B = 1KB: HALF the gather
// instructions of the 4-row layout (tests the VMEM-instr/TA-throughput theory).
// rid shfls per 16-row group: 2 (vs 4). rg-reduce: 3 shfl_xor levels on 8 accs/node
// (+32 DS ops/wave -- proven ~free by the round-10 DS null). -------

template<int SC>
__global__ __launch_bounds__(256) void k_agg(const ushort* __restrict__ xws,
                                             const uint* __restrict__ rowinfo,
                                             const int* __restrict__ csr,
                                             const float* __restrict__ dis,
                                             ushort* __restrict__ hagg,
                                             float* __restrict__ stats) {
    __shared__ float ls[8][64], lq[8][64];
    int tid = threadIdx.x;
    int w = tid >> 6;
    int lane = tid & 63;
    int wid0 = __builtin_amdgcn_readfirstlane(blockIdx.x * 8 + w * 2);   // SGPR
    int wid1 = wid0 + 1;
    int fb = lane & 7;           // 8-feature block: features fb*8 .. fb*8+7 (16B)
    int rg = lane >> 3;          // row subgroup within an 8-row load group

    uint ri0 = rowinfo[wid0];                     // s_load (uniform)
    uint ri1 = rowinfo[wid1];
    int s0 = (int)(ri0 & 0x3FFFFFu), deg0 = (int)(ri0 >> 22);
    int s1 = (int)(ri1 & 0x3FFFFFu), deg1 = (int)(ri1 >> 22);
    float dw0 = dis[wid0], dw1 = dis[wid1];       // s_load (uniform)

    int idx0 = (lane < deg0) ? csr[s0 + lane] : 0;
    int idx1 = (lane < deg1) ? csr[s1 + lane] : 0;
    float dvf0 = 0.f, dvf1 = 0.f;
    if (SC) {
        dvf0 = (lane < deg0) ? dis[idx0] : 0.f;   // pre-masked weights (prefetched)
        dvf1 = (lane < deg1) ? dis[idx1] : 0.f;
    }

    uint4 su0 = *(const uint4*)(xws + (size_t)wid0 * 64 + fb * 8);   // self terms
    uint4 su1 = *(const uint4*)(xws + (size_t)wid1 * 64 + fb * 8);

    float a0 = 0.f, a1 = 0.f, a2 = 0.f, a3 = 0.f, a4 = 0.f, a5 = 0.f, a6 = 0.f, a7 = 0.f;
    float c0 = 0.f, c1 = 0.f, c2 = 0.f, c3 = 0.f, c4 = 0.f, c5 = 0.f, c6 = 0.f, c7 = 0.f;
    int dmax = deg0 > deg1 ? deg0 : deg1;
    int ng = (dmax + 15) >> 4;
    for (int blk = 0; blk < ng; ++blk) {
        int j = blk << 4;
        int sl0 = j + rg, sl1 = j + 8 + rg;
        int r00 = __shfl(idx0, sl0, 64), r01 = __shfl(idx0, sl1, 64);   // ds_bpermute
        int r10 = __shfl(idx1, sl0, 64), r11 = __shfl(idx1, sl1, 64);
        float w00, w01, w10, w11;
        if (SC) {
            w00 = __shfl(dvf0, sl0, 64); w01 = __shfl(dvf0, sl1, 64);
            w10 = __shfl(dvf1, sl0, 64); w11 = __shfl(dvf1, sl1, 64);
        } else {
            w00 = (sl0 < deg0) ? 1.f : 0.f;       // VALU cndmask, no DS op
            w01 = (sl1 < deg0) ? 1.f : 0.f;
            w10 = (sl0 < deg1) ? 1.f : 0.f;
            w11 = (sl1 < deg1) ? 1.f : 0.f;
        }
        uint4 l00 = *(const uint4*)(xws + (size_t)(uint)r00 * 64 + fb * 8);  // 1KB/instr
        uint4 l01 = *(const uint4*)(xws + (size_t)(uint)r01 * 64 + fb * 8);
        uint4 l10 = *(const uint4*)(xws + (size_t)(uint)r10 * 64 + fb * 8);
        uint4 l11 = *(const uint4*)(xws + (size_t)(uint)r11 * 64 + fb * 8);
        ACCUM8(a0,a1,a2,a3,a4,a5,a6,a7, l00, w00)
        ACCUM8(a0,a1,a2,a3,a4,a5,a6,a7, l01, w01)
        ACCUM8(c0,c1,c2,c3,c4,c5,c6,c7, l10, w10)
        ACCUM8(c0,c1,c2,c3,c4,c5,c6,c7, l11, w11)
    }
    // reduce over the 8 row subgroups (lanes sharing fb): xor 8, 16, 32
    a0 += __shfl_xor(a0, 8, 64);  a1 += __shfl_xor(a1, 8, 64);
    a2 += __shfl_xor(a2, 8, 64);  a3 += __shfl_xor(a3, 8, 64);
    a4 += __shfl_xor(a4, 8, 64);  a5 += __shfl_xor(a5, 8, 64);
    a6 += __shfl_xor(a6, 8, 64);  a7 += __shfl_xor(a7, 8, 64);
    c0 += __shfl_xor(c0, 8, 64);  c1 += __shfl_xor(c1, 8, 64);
    c2 += __shfl_xor(c2, 8, 64);  c3 += __shfl_xor(c3, 8, 64);
    c4 += __shfl_xor(c4, 8, 64);  c5 += __shfl_xor(c5, 8, 64);
    c6 += __shfl_xor(c6, 8, 64);  c7 += __shfl_xor(c7, 8, 64);
    a0 += __shfl_xor(a0, 16, 64); a1 += __shfl_xor(a1, 16, 64);
    a2 += __shfl_xor(a2, 16, 64); a3 += __shfl_xor(a3, 16, 64);
    a4 += __shfl_xor(a4, 16, 64); a5 += __shfl_xor(a5, 16, 64);
    a6 += __shfl_xor(a6, 16, 64); a7 += __shfl_xor(a7, 16, 64);
    c0 += __shfl_xor(c0, 16, 64); c1 += __shfl_xor(c1, 16, 64);
    c2 += __shfl_xor(c2, 16, 64); c3 += __shfl_xor(c3, 16, 64);
    c4 += __shfl_xor(c4, 16, 64); c5 += __shfl_xor(c5, 16, 64);
    c6 += __shfl_xor(c6, 16, 64); c7 += __shfl_xor(c7, 16, 64);
    a0 += __shfl_xor(a0, 32, 64); a1 += __shfl_xor(a1, 32, 64);
    a2 += __shfl_xor(a2, 32, 64); a3 += __shfl_xor(a3, 32, 64);
    a4 += __shfl_xor(a4, 32, 64); a5 += __shfl_xor(a5, 32, 64);
    a6 += __shfl_xor(a6, 32, 64); a7 += __shfl_xor(a7, 32, 64);
    c0 += __shfl_xor(c0, 32, 64); c1 += __shfl_xor(c1, 32, 64);
    c2 += __shfl_xor(c2, 32, 64); c3 += __shfl_xor(c3, 32, 64);
    c4 += __shfl_xor(c4, 32, 64); c5 += __shfl_xor(c5, 32, 64);
    c6 += __shfl_xor(c6, 32, 64); c7 += __shfl_xor(c7, 32, 64);

    float sw0 = SC ? dw0 : 1.f;                   // self: xw*dis (SC) -> *dw = dinv
    float sw1 = SC ? dw1 : 1.f;
    float o0 = (a0 + bitsf(su0.x << 16) * sw0) * dw0;
    float o1 = (a1 + bitsf(su0.x & 0xFFFF0000u) * sw0) * dw0;
    float o2 = (a2 + bitsf(su0.y << 16) * sw0) * dw0;
    float o3 = (a3 + bitsf(su0.y & 0xFFFF0000u) * sw0) * dw0;
    float o4 = (a4 + bitsf(su0.z << 16) * sw0) * dw0;
    float o5 = (a5 + bitsf(su0.z & 0xFFFF0000u) * sw0) * dw0;
    float o6 = (a6 + bitsf(su0.w << 16) * sw0) * dw0;
    float o7 = (a7 + bitsf(su0.w & 0xFFFF0000u) * sw0) * dw0;
    float p0 = (c0 + bitsf(su1.x << 16) * sw1) * dw1;
    float p1 = (c1 + bitsf(su1.x & 0xFFFF0000u) * sw1) * dw1;
    float p2 = (c2 + bitsf(su1.y << 16) * sw1) * dw1;
    float p3 = (c3 + bitsf(su1.y & 0xFFFF0000u) * sw1) * dw1;
    float p4 = (c4 + bitsf(su1.z << 16) * sw1) * dw1;
    float p5 = (c5 + bitsf(su1.z & 0xFFFF0000u) * sw1) * dw1;
    float p6 = (c6 + bitsf(su1.w << 16) * sw1) * dw1;
    float p7 = (c7 + bitsf(su1.w & 0xFFFF0000u) * sw1) * dw1;
    uint4 q0; q0.x = f2b2(o0, o1); q0.y = f2b2(o2, o3); q0.z = f2b2(o4, o5); q0.w = f2b2(o6, o7);
    uint4 q1; q1.x = f2b2(p0, p1); q1.y = f2b2(p2, p3); q1.z = f2b2(p4, p5); q1.w = f2b2(p6, p7);
    if (rg == 0) {
        *(uint4*)(hagg + (size_t)wid0 * 64 + fb * 8) = q0;
        *(uint4*)(hagg + (size_t)wid1 * 64 + fb * 8) = q1;
        float r0 = b2fu((ushort)q0.x), r1 = b2fu((ushort)(q0.x >> 16));
        float r2 = b2fu((ushort)q0.y), r3 = b2fu((ushort)(q0.y >> 16));
        float r4 = b2fu((ushort)q0.z), r5 = b2fu((ushort)(q0.z >> 16));
        float r6 = b2fu((ushort)q0.w), r7 = b2fu((ushort)(q0.w >> 16));
        float t0 = b2fu((ushort)q1.x), t1 = b2fu((ushort)(q1.x >> 16));
        float t2 = b2fu((ushort)q1.y), t3 = b2fu((ushort)(q1.y >> 16));
        float t4 = b2fu((ushort)q1.z), t5 = b2fu((ushort)(q1.z >> 16));
        float t6 = b2fu((ushort)q1.w), t7 = b2fu((ushort)(q1.w >> 16));
        float4 rv0; rv0.x = r0; rv0.y = r1; rv0.z = r2; rv0.w = r3;
        float4 rv1; rv1.x = r4; rv1.y = r5; rv1.z = r6; rv1.w = r7;
        float4 qv0; qv0.x = r0*r0; qv0.y = r1*r1; qv0.z = r2*r2; qv0.w = r3*r3;
        float4 qv1; qv1.x = r4*r4; qv1.y = r5*r5; qv1.z = r6*r6; qv1.w = r7*r7;
        float4 sv0; sv0.x = t0; sv0.y = t1; sv0.z = t2; sv0.w = t3;
        float4 sv1; sv1.x = t4; sv1.y = t5; sv1.z = t6; sv1.w = t7;
        float4 uv0; uv0.x = t0*t0; uv0.y = t1*t1; uv0.z = t2*t2; uv0.w = t3*t3;
        float4 uv1; uv1.x = t4*t4; uv1.y = t5*t5; uv1.z = t6*t6; uv1.w = t7*t7;
        *(float4*)&ls[w * 2][fb * 8]     = rv0;
        *(float4*)&ls[w * 2][fb * 8 + 4] = rv1;
        *(float4*)&lq[w * 2][fb * 8]     = qv0;
        *(float4*)&lq[w * 2][fb * 8 + 4] = qv1;
        *(float4*)&ls[w * 2 + 1][fb * 8]     = sv0;
        *(float4*)&ls[w * 2 + 1][fb * 8 + 4] = sv1;
        *(float4*)&lq[w * 2 + 1][fb * 8]     = uv0;
        *(float4*)&lq[w * 2 + 1][fb * 8 + 4] = uv1;
    }
    __syncthreads();
    if (w == 0) {
        int f = lane;
        float sm = (ls[0][f] + ls[1][f]) + (ls[2][f] + ls[3][f])
                 + (ls[4][f] + ls[5][f]) + (ls[6][f] + ls[7][f]);
        float q  = (lq[0][f] + lq[1][f]) + (lq[2][f] + lq[3][f])
                 + (lq[4][f] + lq[5][f]) + (lq[6][f] + lq[7][f]);
        float* sl2 = stats + (blockIdx.x & (NSLICE - 1)) * 128;
        atomicAdd(&sl2[f], sm);
        atomicAdd(&sl2[64 + f], q);
    }
}

// ------- fused BN+ReLU + mean-pool + MLP head + log_softmax.
// Stats reduce spread across 256 threads (NSLICE/4 loads each) + LDS combine. -------

__global__ __launch_bounds__(256) void k_poolhead(const ushort* __restrict__ hagg,
                                                  const float* __restrict__ stats,
                                                  const void* __restrict__ gam,
                                                  const void* __restrict__ bet,
                                                  const int* __restrict__ batch,
                                                  const void* __restrict__ fc1w,
                                                  const void* __restrict__ fc1b,
                                                  const void* __restrict__ fc2w,
                                                  const void* __restrict__ fc2b,
                                                  void* __restrict__ out,
                                                  const int* __restrict__ flag) {
    __shared__ float part[4][64];
    __shared__ float stg[512];
    __shared__ float pooled[64], z1[32], z2[10], slse;
    int bf = *flag;
    int g = blockIdx.x, tid = threadIdx.x;
    int w = tid >> 6, f = tid & 63;
    int lo = 0, hi = NN;
    while (lo < hi) { int mid = (lo + hi) >> 1; if (batch[mid] < g) lo = mid + 1; else hi = mid; }
    int s = lo;
    hi = NN;
    while (lo < hi) { int mid = (lo + hi) >> 1; if (batch[mid] < g + 1) lo = mid + 1; else hi = mid; }
    int e = lo;
    {
        float se = 0.f, sq = 0.f;
        #pragma unroll
        for (int k = 0; k < NSLICE / 4; ++k) {
            int sl = w * (NSLICE / 4) + k;
            se += stats[sl * 128 + f];
            sq += stats[sl * 128 + 64 + f];
        }
        stg[w * 64 + f] = se;
        stg[256 + w * 64 + f] = sq;
    }
    __syncthreads();
    float se4 = stg[f] + stg[64 + f] + stg[128 + f] + stg[192 + f];
    float sq4 = stg[256 + f] + stg[320 + f] + stg[384 + f] + stg[448 + f];
    float m = se4 * (1.0f / NN);
    float v = sq4 * (1.0f / NN) - m * m;
    float sc = rsqrtf(v + 1e-5f) * ldin(gam, f, bf);
    float sh = ldin(bet, f, bf) - m * sc;
    float acc = 0.f;
    for (int r = s + w; r < e; r += 4)
        acc += fmaxf(fmaf(b2fu(hagg[(size_t)r * 64 + f]), sc, sh), 0.f);
    part[w][f] = acc;
    __syncthreads();
    if (w == 0)
        pooled[f] = (part[0][f] + part[1][f] + part[2][f] + part[3][f])
                  / fmaxf((float)(e - s), 1.0f);
    __syncthreads();
    if (tid < 32) {
        float a = ldin(fc1b, tid, bf);
        for (int k = 0; k < 64; ++k) a += pooled[k] * ldin(fc1w, k * 32 + tid, bf);
        z1[tid] = fmaxf(a, 0.f);
    }
    __syncthreads();
    if (tid < 10) {
        float a = ldin(fc2b, tid, bf);
        for (int k = 0; k < 32; ++k) a += z1[k] * ldin(fc2w, k * 10 + tid, bf);
        z2[tid] = a;
    }
    __syncthreads();
    if (tid == 0) {
        float mm = z2[0];
        for (int c = 1; c < 10; ++c) mm = fmaxf(mm, z2[c]);
        float ss = 0.f;
        for (int c = 0; c < 10; ++c) ss += expf(z2[c] - mm);
        slse = mm + logf(ss);
    }
    __syncthreads();
    if (tid < 10) stout(out, g * 10 + tid, z2[tid] - slse, bf);
}

// ---------------- launch ----------------

extern "C" void kernel_launch(void* const* d_in, const int* in_sizes, int n_in,
                              void* d_out, int out_size, void* d_ws, size_t ws_size,
                              hipStream_t stream) {
    const void* x     = d_in[0];
    const int*  ei    = (const int*)d_in[1];
    const int*  batch = (const int*)d_in[2];
    const int* srcp = ei;
    const int* dstp = ei + EE;
    const void* W[3]   = {d_in[3],  d_in[7],  d_in[11]};
    const void* gg_[3] = {d_in[5],  d_in[9],  d_in[13]};
    const void* be_[3] = {d_in[6],  d_in[10], d_in[14]};
    const void* fc1w = d_in[15];
    const void* fc1b = d_in[16];
    const void* fc2w = d_in[17];
    const void* fc2b = d_in[18];

    char* ws = (char*)d_ws;
    size_t off = 0;
    auto alloc = [&](size_t bytes) { size_t o = off; off = (off + bytes + 255) & ~(size_t)255; return o; };
    ushort* xws     = (ushort*)(ws + alloc((size_t)NN * HH * 2));
    ushort* hagg    = (ushort*)(ws + alloc((size_t)NN * HH * 2));
    uint*   ebuf    = (uint*)  (ws + alloc((size_t)NB_BUCKET * BCAP * 4));
    int*    csr     = (int*)   (ws + alloc(((size_t)NB_BUCKET * BCAP + 64) * 4));
    uint*   rowinfo = (uint*)  (ws + alloc((size_t)NN * 4));
    float*  dis     = (float*) (ws + alloc((size_t)NN * 4));
    uint4*  wpack   = (uint4*) (ws + alloc((size_t)3 * 512 * 16));
    size_t  zoff    = alloc((size_t)NB_BUCKET * 4);          // bcur (zeroed)
    int*    bcur    = (int*)(ws + zoff);
    float*  stats   = (float*) (ws + alloc((size_t)3 * NSLICE * 128 * 4));  // zeroed
    size_t  zend    = off;
    int*    dflag   = (int*)   (ws + alloc(256));
    if (off > ws_size) return;

    const int AB = NN / 8;            // 12500 blocks, 2 nodes per wave, 8 per block
    const int SL = NSLICE * 128;
    const int ZQ = (int)((zend - zoff) / 16);

    // prep: flag + zero(bcur,stats) + pack W0/W1/W2 into MFMA fragment layout
    k_prep<<<17, 256, 0, stream>>>((const uint*)x, W[0], W[1], W[2], dflag, wpack,
                                   (uint4*)(ws + zoff), ZQ);
    // edge bucket-scatter (512t, proven-fast config)
    k_bscatter<<<192, 512, 0, stream>>>(srcp, dstp, bcur, ebuf);
    // fused: bucket counting-sort  ||  layer-0 GEMM (both depend only on scatter)
    k_bg0<<<NB_BUCKET + GB, 256, 0, stream>>>(x, wpack, xws, dflag, ebuf, bcur,
                                              rowinfo, dis, csr);

    k_agg<1><<<AB, 256, 0, stream>>>(xws, rowinfo, csr, dis, hagg, stats);

    k_gemm1<<<GB, 256, 0, stream>>>(hagg, wpack + 512, stats, gg_[0], be_[0], dis, xws, dflag);
    k_agg<0><<<AB, 256, 0, stream>>>(xws, rowinfo, csr, dis, hagg, stats + SL);

    k_gemm1<<<GB, 256, 0, stream>>>(hagg, wpack + 1024, stats + SL, gg_[1], be_[1], dis, xws, dflag);
    k_agg<0><<<AB, 256, 0, stream>>>(xws, rowinfo, csr, dis, hagg, stats + 2 * SL);

    k_poolhead<<<GG, 256, 0, stream>>>(hagg, stats + 2 * SL, gg_[2], be_[2], batch,
                                       fc1w, fc1b, fc2w, fc2b, d_out, dflag);
}

// Round 12
// 274.763 us; speedup vs baseline: 1.1373x; 1.1373x over previous
//
#include <hip/hip_runtime.h>
#include <hip/hip_bf16.h>

#define NN 100000
#define EE 1200000
#define HH 64
#define CC 10
#define GG 1000
#define NB_BUCKET 782          // ceil(NN/128)
#define BCAP 3072              // bucket capacity (mean 1536)
#define NSLICE 64              // stats atomic slices
#define GB 1563                // (NN+63)/64 gemm tiles

typedef unsigned int uint;
typedef unsigned short ushort;
typedef __attribute__((ext_vector_type(8))) short short8;   // 8 bf16 (4 VGPRs)
typedef __attribute__((ext_vector_type(4))) float f32x4;

// ---------- helpers ----------

__device__ __forceinline__ float b2fu(ushort u) {
    uint w = ((uint)u) << 16;
    float f; __builtin_memcpy(&f, &w, 4); return f;
}
__device__ __forceinline__ uint fbits(float f) { uint w; __builtin_memcpy(&w, &f, 4); return w; }
__device__ __forceinline__ float bitsf(uint w) { float f; __builtin_memcpy(&f, &w, 4); return f; }
__device__ __forceinline__ ushort f2b(float f) {
    uint w = fbits(f);
    w += 0x7FFFu + ((w >> 16) & 1u);
    return (ushort)(w >> 16);
}
__device__ __forceinline__ uint f2b2(float lo, float hi) {
    uint a = fbits(lo), b = fbits(hi);
    a += 0x7FFFu + ((a >> 16) & 1u);
    b += 0x7FFFu + ((b >> 16) & 1u);
    return (a >> 16) | (b & 0xFFFF0000u);
}
__device__ __forceinline__ float ldin(const void* p, int i, int bf) {
    if (bf) return b2fu(((const ushort*)p)[i]);
    return ((const float*)p)[i];
}
__device__ __forceinline__ void stout(void* p, int i, float v, int bf) {
    if (bf) ((ushort*)p)[i] = f2b(v);
    else    ((float*)p)[i] = v;
}
__device__ __forceinline__ short8 pack8(const float* v) {
    uint4 u;
    u.x = f2b2(v[0], v[1]); u.y = f2b2(v[2], v[3]);
    u.z = f2b2(v[4], v[5]); u.w = f2b2(v[6], v[7]);
    short8 r; __builtin_memcpy(&r, &u, 16); return r;
}

// ---------------- prep: detect flag + zero bcur/stats + pre-pack W fragments ----------------
// W pack layout per matrix: 512 x uint4, index (t*2+q)*64 + l.

__global__ __launch_bounds__(256) void k_prep(const uint* __restrict__ x,
                                              const void* __restrict__ W0,
                                              const void* __restrict__ W1,
                                              const void* __restrict__ W2,
                                              int* __restrict__ flag,
                                              uint4* __restrict__ wpack,
                                              uint4* __restrict__ zp, int zq) {
    __shared__ int c2[2];
    __shared__ int cnt;
    int b = blockIdx.x, tid = threadIdx.x;
    if (b == 0) {
        if (tid == 0) cnt = 0;
        __syncthreads();
        if (tid < 128) {
            uint v = x[tid];
            int e = (v >> 7) & 0xFF;
            if (e >= 100 && e <= 133) atomicAdd(&cnt, 1);
        }
        __syncthreads();
        if (tid == 0) *flag = (cnt >= 96) ? 1 : 0;
    } else if (b <= 3) {
        // local bf16 detect (no cross-block dependency on flag)
        if (tid < 128) {
            uint v = x[tid];
            int e = (v >> 7) & 0xFF;
            unsigned long long m = __ballot(e >= 100 && e <= 133);
            if ((tid & 63) == 0) c2[tid >> 6] = (int)__popcll(m);
        }
        __syncthreads();
        int bf = (c2[0] + c2[1]) >= 96;
        const void* Wp = (b == 1) ? W0 : (b == 2) ? W1 : W2;
        uint4* wdst = wpack + (b - 1) * 512;
        for (int slot = tid; slot < 512; slot += 256) {
            int l = slot & 63, q = (slot >> 6) & 1, t = slot >> 7;
            int quad = l >> 4, n = l & 15;
            int ks = q * 32 + quad * 8;
            int col = t * 16 + n;
            float wv[8];
            #pragma unroll
            for (int j = 0; j < 8; ++j) wv[j] = ldin(Wp, (ks + j) * 64 + col, bf);
            uint4 u;
            u.x = f2b2(wv[0], wv[1]); u.y = f2b2(wv[2], wv[3]);
            u.z = f2b2(wv[4], wv[5]); u.w = f2b2(wv[6], wv[7]);
            wdst[(t * 2 + q) * 64 + l] = u;
        }
    } else {
        uint4 z4 = {0u, 0u, 0u, 0u};
        for (int i = (b - 4) * 256 + tid; i < zq; i += ((int)gridDim.x - 4) * 256)
            zp[i] = z4;
    }
}

// ---------------- edge scatter (stand-alone, 512 threads: proven config) ----------------

__global__ __launch_bounds__(512) void k_bscatter(const int* __restrict__ src,
                                                  const int* __restrict__ dst,
                                                  int* __restrict__ bcur,
                                                  uint* __restrict__ ebuf) {
    __shared__ int hist[NB_BUCKET];
    __shared__ int base[NB_BUCKET];
    int tid = threadIdx.x;
    const int chunk = (EE + gridDim.x - 1) / gridDim.x;
    int e0 = blockIdx.x * chunk;
    int e1 = e0 + chunk; if (e1 > EE) e1 = EE;
    for (int i = tid; i < NB_BUCKET; i += 512) hist[i] = 0;
    __syncthreads();
    for (int e = e0 + tid; e < e1; e += 512)
        atomicAdd(&hist[dst[e] >> 7], 1);
    __syncthreads();
    for (int b = tid; b < NB_BUCKET; b += 512) {
        int c = hist[b];
        base[b] = c ? (b * BCAP + atomicAdd(&bcur[b], c)) : 0;
        hist[b] = 0;
    }
    __syncthreads();
    for (int e = e0 + tid; e < e1; e += 512) {
        int d = dst[e];
        int b = d >> 7;
        int r = atomicAdd(&hist[b], 1);
        ebuf[base[b] + r] = (uint)src[e] | (((uint)d & 127u) << 17);
    }
}

// ---------------- shared-memory layouts ----------------

struct GemmSh {
    ushort Ct[64][64];           // epilogue transpose (8KB); aliased as f32 staging in MODE1 prologue
    float scA[64], shA[64];
};
struct BsortSh {
    int hist[128], sc[128], cur[128];
    int s_src[BCAP];
};
union BgU { GemmSh g; BsortSh b; };

// ---------------- bucket counting sort (256-thread variant, fused into bg0) ----------------

__device__ __forceinline__ void dev_bsort(const uint* __restrict__ ebuf,
                                          const int* __restrict__ bcur,
                                          uint* __restrict__ rowinfo,
                                          float* __restrict__ dis,
                                          int* __restrict__ csr,
                                          BsortSh& sh, int b) {
    int tid = threadIdx.x;
    int n0 = b << 7;
    int ebase = b * BCAP;
    int ecnt = bcur[b];
    if (ecnt > BCAP) ecnt = BCAP;
    if (tid < 128) sh.hist[tid] = 0;
    __syncthreads();
    for (int i = tid; i < ecnt; i += 256)
        atomicAdd(&sh.hist[ebuf[ebase + i] >> 17], 1);
    __syncthreads();
    if (tid < 128) sh.sc[tid] = sh.hist[tid];
    __syncthreads();
    for (int off = 1; off < 128; off <<= 1) {
        int t = (tid < 128 && tid >= off) ? sh.sc[tid - off] : 0;
        __syncthreads();
        if (tid < 128) sh.sc[tid] += t;
        __syncthreads();
    }
    if (tid < 128) {
        int excl = sh.sc[tid] - sh.hist[tid];
        sh.cur[tid] = excl;
        int node = n0 + tid;
        if (node < NN) {
            int dcap = sh.hist[tid] > 64 ? 64 : sh.hist[tid];
            rowinfo[node] = (uint)(ebase + excl) | ((uint)dcap << 22);
            dis[node] = rsqrtf((float)sh.hist[tid] + 1.0f);
        }
    }
    __syncthreads();
    for (int i = tid; i < ecnt; i += 256) {
        uint ed = ebuf[ebase + i];
        int p = atomicAdd(&sh.cur[ed >> 17], 1);
        sh.s_src[p] = (int)(ed & 0x1FFFFu);
    }
    __syncthreads();
    for (int i = tid; i < ecnt; i += 256)
        csr[ebase + i] = sh.s_src[i];
}

// ------- MFMA GEMM body. MODE 0: raw xw (NO dis scale; layer-0 agg applies it).
//         MODE 1: BN+ReLU on A, dis-scaled output. B-frags read directly from wpack (L2).
//         MODE 1 stats reduce: NSLICE/4 loads/thread across 256 threads + LDS combine. -------

template<int MODE>
__device__ __forceinline__ void dev_gemm(const void* __restrict__ A,
                                         const uint4* __restrict__ wp,
                                         const float* __restrict__ stats,
                                         const void* __restrict__ gam,
                                         const void* __restrict__ bet,
                                         const float* __restrict__ dis,
                                         ushort* __restrict__ outb,
                                         const int* __restrict__ flag,
                                         GemmSh& sh, int bx) {
    int bf = *flag;
    int tid = threadIdx.x;
    int row0 = bx * 64;

    if (MODE == 1) {
        float* stg = (float*)sh.Ct;              // 512 f32 staging (Ct reused later)
        int f = tid & 63, grp = tid >> 6;
        float se = 0.f, sq = 0.f;
        #pragma unroll
        for (int k = 0; k < NSLICE / 4; ++k) {
            int sl = grp * (NSLICE / 4) + k;
            se += stats[sl * 128 + f];
            sq += stats[sl * 128 + 64 + f];
        }
        stg[grp * 64 + f] = se;
        stg[256 + grp * 64 + f] = sq;
        __syncthreads();
        if (tid < 64) {
            float se4 = stg[tid] + stg[64 + tid] + stg[128 + tid] + stg[192 + tid];
            float sq4 = stg[256 + tid] + stg[320 + tid] + stg[384 + tid] + stg[448 + tid];
            float m = se4 * (1.0f / NN);
            float v = sq4 * (1.0f / NN) - m * m;
            float s = rsqrtf(v + 1e-5f) * ldin(gam, tid, bf);
            sh.scA[tid] = s;
            sh.shA[tid] = ldin(bet, tid, bf) - m * s;
        }
        __syncthreads();
    }

    int w = tid >> 6, lane = tid & 63;
    int quad = lane >> 4, mrow = lane & 15;
    int grow = row0 + w * 16 + mrow;
    int arow = (grow < NN) ? grow : 0;

    short8 a0, a1;
    if (MODE == 0) {
        if (bf) {
            const uint4* ap = (const uint4*)((const ushort*)A + (size_t)arow * 64);
            uint4 u0 = ap[quad], u1 = ap[4 + quad];
            __builtin_memcpy(&a0, &u0, 16);
            __builtin_memcpy(&a1, &u1, 16);
        } else {
            const float4* ap = (const float4*)((const float*)A + (size_t)arow * 64);
            float4 f0 = ap[quad * 2], f1 = ap[quad * 2 + 1];
            float4 f2 = ap[8 + quad * 2], f3 = ap[9 + quad * 2];
            float v0[8] = {f0.x, f0.y, f0.z, f0.w, f1.x, f1.y, f1.z, f1.w};
            float v1[8] = {f2.x, f2.y, f2.z, f2.w, f3.x, f3.y, f3.z, f3.w};
            a0 = pack8(v0);
            a1 = pack8(v1);
        }
    } else {
        const uint4* ap = (const uint4*)((const ushort*)A + (size_t)arow * 64);
        uint4 u0 = ap[quad], u1 = ap[4 + quad];
        const float4* sc4 = (const float4*)sh.scA;
        const float4* sh4 = (const float4*)sh.shA;
        float4 sa = sc4[quad * 2],     sb2 = sc4[quad * 2 + 1];
        float4 ha = sh4[quad * 2],     hb = sh4[quad * 2 + 1];
        float4 sa1 = sc4[8 + quad * 2], sb1 = sc4[9 + quad * 2];
        float4 ha1 = sh4[8 + quad * 2], hb1 = sh4[9 + quad * 2];
        float v0[8], v1[8];
        v0[0]=bitsf(u0.x<<16); v0[1]=bitsf(u0.x&0xFFFF0000u);
        v0[2]=bitsf(u0.y<<16); v0[3]=bitsf(u0.y&0xFFFF0000u);
        v0[4]=bitsf(u0.z<<16); v0[5]=bitsf(u0.z&0xFFFF0000u);
        v0[6]=bitsf(u0.w<<16); v0[7]=bitsf(u0.w&0xFFFF0000u);
        v1[0]=bitsf(u1.x<<16); v1[1]=bitsf(u1.x&0xFFFF0000u);
        v1[2]=bitsf(u1.y<<16); v1[3]=bitsf(u1.y&0xFFFF0000u);
        v1[4]=bitsf(u1.z<<16); v1[5]=bitsf(u1.z&0xFFFF0000u);
        v1[6]=bitsf(u1.w<<16); v1[7]=bitsf(u1.w&0xFFFF0000u);
        v0[0]=fmaxf(fmaf(v0[0],sa.x,ha.x),0.f); v0[1]=fmaxf(fmaf(v0[1],sa.y,ha.y),0.f);
        v0[2]=fmaxf(fmaf(v0[2],sa.z,ha.z),0.f); v0[3]=fmaxf(fmaf(v0[3],sa.w,ha.w),0.f);
        v0[4]=fmaxf(fmaf(v0[4],sb2.x,hb.x),0.f); v0[5]=fmaxf(fmaf(v0[5],sb2.y,hb.y),0.f);
        v0[6]=fmaxf(fmaf(v0[6],sb2.z,hb.z),0.f); v0[7]=fmaxf(fmaf(v0[7],sb2.w,hb.w),0.f);
        v1[0]=fmaxf(fmaf(v1[0],sa1.x,ha1.x),0.f); v1[1]=fmaxf(fmaf(v1[1],sa1.y,ha1.y),0.f);
        v1[2]=fmaxf(fmaf(v1[2],sa1.z,ha1.z),0.f); v1[3]=fmaxf(fmaf(v1[3],sa1.w,ha1.w),0.f);
        v1[4]=fmaxf(fmaf(v1[4],sb1.x,hb1.x),0.f); v1[5]=fmaxf(fmaf(v1[5],sb1.y,hb1.y),0.f);
        v1[6]=fmaxf(fmaf(v1[6],sb1.z,hb1.z),0.f); v1[7]=fmaxf(fmaf(v1[7],sb1.w,hb1.w),0.f);
        a0 = pack8(v0);
        a1 = pack8(v1);
    }

    f32x4 acc[4];
    #pragma unroll
    for (int t = 0; t < 4; ++t) {
        short8 b0, b1;
        uint4 ub0 = wp[(t * 2) * 64 + lane], ub1 = wp[(t * 2 + 1) * 64 + lane];
        __builtin_memcpy(&b0, &ub0, 16);
        __builtin_memcpy(&b1, &ub1, 16);
        f32x4 z = {0.f, 0.f, 0.f, 0.f};
        f32x4 c = __builtin_amdgcn_mfma_f32_16x16x32_bf16(a0, b0, z, 0, 0, 0);
        acc[t] = __builtin_amdgcn_mfma_f32_16x16x32_bf16(a1, b1, c, 0, 0, 0);
    }

    float dd[4];
    #pragma unroll
    for (int r = 0; r < 4; ++r) {
        if (MODE == 1) {
            int gr = row0 + w * 16 + quad * 4 + r;
            dd[r] = (gr < NN) ? dis[gr] : 0.f;
        } else dd[r] = 1.f;
    }
    #pragma unroll
    for (int t = 0; t < 4; ++t)
        #pragma unroll
        for (int r = 0; r < 4; ++r)
            sh.Ct[w * 16 + quad * 4 + r][t * 16 + mrow] = f2b(acc[t][r] * dd[r]);
    __syncthreads();

    int orow = tid >> 2, oc = (tid & 3) * 16;
    int growo = row0 + orow;
    if (growo < NN) {
        const uint4* lp = (const uint4*)&sh.Ct[orow][oc];
        uint4 q0 = lp[0], q1 = lp[1];
        uint4* op = (uint4*)(outb + (size_t)growo * 64 + oc);
        op[0] = q0; op[1] = q1;
    }
}

// fused: bucket sort (blocks [0,NB_BUCKET)) || layer-0 GEMM (blocks [NB_BUCKET, NB_BUCKET+GB))
__global__ __launch_bounds__(256) void k_bg0(const void* __restrict__ A,
                                             const uint4* __restrict__ wpack,
                                             ushort* __restrict__ xws,
                                             const int* __restrict__ flag,
                                             const uint* __restrict__ ebuf,
                                             const int* __restrict__ bcur,
                                             uint* __restrict__ rowinfo,
                                             float* __restrict__ dis,
                                             int* __restrict__ csr) {
    __shared__ BgU sh;
    int bx = blockIdx.x;
    if (bx < NB_BUCKET)
        dev_bsort(ebuf, bcur, rowinfo, dis, csr, sh.b, bx);
    else
        dev_gemm<0>(A, wpack, nullptr, nullptr, nullptr, nullptr, xws, flag, sh.g, bx - NB_BUCKET);
}

__global__ __launch_bounds__(256) void k_gemm1(const void* __restrict__ A,
                                               const uint4* __restrict__ wp,
                                               const float* __restrict__ stats,
                                               const void* __restrict__ gam,
                                               const void* __restrict__ bet,
                                               const float* __restrict__ dis,
                                               ushort* __restrict__ outb,
                                               const int* __restrict__ flag) {
    __shared__ GemmSh sh;
    dev_gemm<1>(A, wp, stats, gam, bet, dis, outb, flag, sh, blockIdx.x);
}

// ------- aggregate + fused BN stats — TWO nodes per wave, 4 rows per gather
// (round-10 known-good: best occupancy/ILP balance; 8-row variant refuted
// r11 — VGPR 44 / occ 44% / bank conflicts; 4-node refuted r8; fixed-stride
// refuted r9; gather is cache-line-transaction bound, occupancy-sensitive).
// SC=0 weights by arithmetic compare (no DS op); SC=1 prefetch+shfl. -------

template<int SC>
__global__ __launch_bounds__(256) void k_agg(const ushort* __restrict__ xws,
                                             const uint* __restrict__ rowinfo,
                                             const int* __restrict__ csr,
                                             const float* __restrict__ dis,
                                             ushort* __restrict__ hagg,
                                             float* __restrict__ stats) {
    __shared__ float ls[8][64], lq[8][64];
    int tid = threadIdx.x;
    int w = tid >> 6;
    int lane = tid & 63;
    int wid0 = __builtin_amdgcn_readfirstlane(blockIdx.x * 8 + w * 2);   // SGPR
    int wid1 = wid0 + 1;
    int fb = lane & 15;          // feature block: features fb*4 .. fb*4+3
    int rg = lane >> 4;          // row subgroup within a 4-row load group

    uint ri0 = rowinfo[wid0];                     // s_load (uniform)
    uint ri1 = rowinfo[wid1];
    int s0 = (int)(ri0 & 0x3FFFFFu), deg0 = (int)(ri0 >> 22);
    int s1 = (int)(ri1 & 0x3FFFFFu), deg1 = (int)(ri1 >> 22);
    float dw0 = dis[wid0], dw1 = dis[wid1];       // s_load (uniform)

    int idx0 = (lane < deg0) ? csr[s0 + lane] : 0;
    int idx1 = (lane < deg1) ? csr[s1 + lane] : 0;
    float dvf0 = 0.f, dvf1 = 0.f;
    if (SC) {
        dvf0 = (lane < deg0) ? dis[idx0] : 0.f;   // pre-masked weights (prefetched)
        dvf1 = (lane < deg1) ? dis[idx1] : 0.f;
    }

    uint2 su0 = *(const uint2*)(xws + (size_t)wid0 * 64 + fb * 4);   // self terms
    uint2 su1 = *(const uint2*)(xws + (size_t)wid1 * 64 + fb * 4);

    float a0 = 0.f, a1 = 0.f, a2 = 0.f, a3 = 0.f;
    float c0 = 0.f, c1 = 0.f, c2 = 0.f, c3 = 0.f;
    int dmax = deg0 > deg1 ? deg0 : deg1;
    int ng = (dmax + 15) >> 4;
    for (int blk = 0; blk < ng; ++blk) {
        int j = blk << 4;
        int rid0[4], rid1[4]; float wv0[4], wv1[4]; uint2 lu0[4], lu1[4];
        #pragma unroll
        for (int sub = 0; sub < 4; ++sub) {
            int sl = j + sub * 4 + rg;
            rid0[sub] = __shfl(idx0, sl, 64);     // ds_bpermute (addr reg shared)
            rid1[sub] = __shfl(idx1, sl, 64);
            if (SC) {
                wv0[sub] = __shfl(dvf0, sl, 64);
                wv1[sub] = __shfl(dvf1, sl, 64);
            } else {
                wv0[sub] = (sl < deg0) ? 1.f : 0.f;   // VALU cndmask, no DS op
                wv1[sub] = (sl < deg1) ? 1.f : 0.f;
            }
        }
        #pragma unroll
        for (int sub = 0; sub < 4; ++sub) {
            lu0[sub] = *(const uint2*)(xws + (size_t)(uint)rid0[sub] * 64 + fb * 4);
            lu1[sub] = *(const uint2*)(xws + (size_t)(uint)rid1[sub] * 64 + fb * 4);
        }
        #pragma unroll
        for (int sub = 0; sub < 4; ++sub) {
            float f0 = bitsf(lu0[sub].x << 16), f1 = bitsf(lu0[sub].x & 0xFFFF0000u);
            float f2 = bitsf(lu0[sub].y << 16), f3 = bitsf(lu0[sub].y & 0xFFFF0000u);
            a0 = fmaf(f0, wv0[sub], a0);
            a1 = fmaf(f1, wv0[sub], a1);
            a2 = fmaf(f2, wv0[sub], a2);
            a3 = fmaf(f3, wv0[sub], a3);
            float g0 = bitsf(lu1[sub].x << 16), g1 = bitsf(lu1[sub].x & 0xFFFF0000u);
            float g2 = bitsf(lu1[sub].y << 16), g3 = bitsf(lu1[sub].y & 0xFFFF0000u);
            c0 = fmaf(g0, wv1[sub], c0);
            c1 = fmaf(g1, wv1[sub], c1);
            c2 = fmaf(g2, wv1[sub], c2);
            c3 = fmaf(g3, wv1[sub], c3);
        }
    }
    // reduce over the 4 row subgroups (lanes sharing fb)
    a0 += __shfl_xor(a0, 16, 64); a1 += __shfl_xor(a1, 16, 64);
    a2 += __shfl_xor(a2, 16, 64); a3 += __shfl_xor(a3, 16, 64);
    c0 += __shfl_xor(c0, 16, 64); c1 += __shfl_xor(c1, 16, 64);
    c2 += __shfl_xor(c2, 16, 64); c3 += __shfl_xor(c3, 16, 64);
    a0 += __shfl_xor(a0, 32, 64); a1 += __shfl_xor(a1, 32, 64);
    a2 += __shfl_xor(a2, 32, 64); a3 += __shfl_xor(a3, 32, 64);
    c0 += __shfl_xor(c0, 32, 64); c1 += __shfl_xor(c1, 32, 64);
    c2 += __shfl_xor(c2, 32, 64); c3 += __shfl_xor(c3, 32, 64);

    float sw0 = SC ? dw0 : 1.f;                   // self: xw*dis (SC) -> *dw = dinv
    float sw1 = SC ? dw1 : 1.f;
    float o0 = (a0 + bitsf(su0.x << 16) * sw0) * dw0;
    float o1 = (a1 + bitsf(su0.x & 0xFFFF0000u) * sw0) * dw0;
    float o2 = (a2 + bitsf(su0.y << 16) * sw0) * dw0;
    float o3 = (a3 + bitsf(su0.y & 0xFFFF0000u) * sw0) * dw0;
    float p0f = (c0 + bitsf(su1.x << 16) * sw1) * dw1;
    float p1f = (c1 + bitsf(su1.x & 0xFFFF0000u) * sw1) * dw1;
    float p2f = (c2 + bitsf(su1.y << 16) * sw1) * dw1;
    float p3f = (c3 + bitsf(su1.y & 0xFFFF0000u) * sw1) * dw1;
    uint q0 = f2b2(o0, o1), q1 = f2b2(o2, o3);
    uint q2 = f2b2(p0f, p1f), q3 = f2b2(p2f, p3f);
    if (rg == 0) {
        uint2 st0; st0.x = q0; st0.y = q1;
        uint2 st1; st1.x = q2; st1.y = q3;
        *(uint2*)(hagg + (size_t)wid0 * 64 + fb * 4) = st0;
        *(uint2*)(hagg + (size_t)wid1 * 64 + fb * 4) = st1;
        float r0 = b2fu((ushort)q0), r1 = b2fu((ushort)(q0 >> 16));
        float r2 = b2fu((ushort)q1), r3 = b2fu((ushort)(q1 >> 16));
        float t0 = b2fu((ushort)q2), t1 = b2fu((ushort)(q2 >> 16));
        float t2 = b2fu((ushort)q3), t3 = b2fu((ushort)(q3 >> 16));
        float4 rv; rv.x = r0; rv.y = r1; rv.z = r2; rv.w = r3;
        float4 qv; qv.x = r0 * r0; qv.y = r1 * r1; qv.z = r2 * r2; qv.w = r3 * r3;
        float4 rv1; rv1.x = t0; rv1.y = t1; rv1.z = t2; rv1.w = t3;
        float4 qv1; qv1.x = t0 * t0; qv1.y = t1 * t1; qv1.z = t2 * t2; qv1.w = t3 * t3;
        *(float4*)&ls[w * 2][fb * 4] = rv;
        *(float4*)&lq[w * 2][fb * 4] = qv;
        *(float4*)&ls[w * 2 + 1][fb * 4] = rv1;
        *(float4*)&lq[w * 2 + 1][fb * 4] = qv1;
    }
    __syncthreads();
    if (w == 0) {
        int f = lane;
        float sm = (ls[0][f] + ls[1][f]) + (ls[2][f] + ls[3][f])
                 + (ls[4][f] + ls[5][f]) + (ls[6][f] + ls[7][f]);
        float q  = (lq[0][f] + lq[1][f]) + (lq[2][f] + lq[3][f])
                 + (lq[4][f] + lq[5][f]) + (lq[6][f] + lq[7][f]);
        float* sl2 = stats + (blockIdx.x & (NSLICE - 1)) * 128;
        atomicAdd(&sl2[f], sm);
        atomicAdd(&sl2[64 + f], q);
    }
}

// ------- fused BN+ReLU + mean-pool + MLP head + log_softmax.
// Stats reduce spread across 256 threads (NSLICE/4 loads each) + LDS combine. -------

__global__ __launch_bounds__(256) void k_poolhead(const ushort* __restrict__ hagg,
                                                  const float* __restrict__ stats,
                                                  const void* __restrict__ gam,
                                                  const void* __restrict__ bet,
                                                  const int* __restrict__ batch,
                                                  const void* __restrict__ fc1w,
                                                  const void* __restrict__ fc1b,
                                                  const void* __restrict__ fc2w,
                                                  const void* __restrict__ fc2b,
                                                  void* __restrict__ out,
                                                  const int* __restrict__ flag) {
    __shared__ float part[4][64];
    __shared__ float stg[512];
    __shared__ float pooled[64], z1[32], z2[10], slse;
    int bf = *flag;
    int g = blockIdx.x, tid = threadIdx.x;
    int w = tid >> 6, f = tid & 63;
    int lo = 0, hi = NN;
    while (lo < hi) { int mid = (lo + hi) >> 1; if (batch[mid] < g) lo = mid + 1; else hi = mid; }
    int s = lo;
    hi = NN;
    while (lo < hi) { int mid = (lo + hi) >> 1; if (batch[mid] < g + 1) lo = mid + 1; else hi = mid; }
    int e = lo;
    {
        float se = 0.f, sq = 0.f;
        #pragma unroll
        for (int k = 0; k < NSLICE / 4; ++k) {
            int sl = w * (NSLICE / 4) + k;
            se += stats[sl * 128 + f];
            sq += stats[sl * 128 + 64 + f];
        }
        stg[w * 64 + f] = se;
        stg[256 + w * 64 + f] = sq;
    }
    __syncthreads();
    float se4 = stg[f] + stg[64 + f] + stg[128 + f] + stg[192 + f];
    float sq4 = stg[256 + f] + stg[320 + f] + stg[384 + f] + stg[448 + f];
    float m = se4 * (1.0f / NN);
    float v = sq4 * (1.0f / NN) - m * m;
    float sc = rsqrtf(v + 1e-5f) * ldin(gam, f, bf);
    float sh = ldin(bet, f, bf) - m * sc;
    float acc = 0.f;
    for (int r = s + w; r < e; r += 4)
        acc += fmaxf(fmaf(b2fu(hagg[(size_t)r * 64 + f]), sc, sh), 0.f);
    part[w][f] = acc;
    __syncthreads();
    if (w == 0)
        pooled[f] = (part[0][f] + part[1][f] + part[2][f] + part[3][f])
                  / fmaxf((float)(e - s), 1.0f);
    __syncthreads();
    if (tid < 32) {
        float a = ldin(fc1b, tid, bf);
        for (int k = 0; k < 64; ++k) a += pooled[k] * ldin(fc1w, k * 32 + tid, bf);
        z1[tid] = fmaxf(a, 0.f);
    }
    __syncthreads();
    if (tid < 10) {
        float a = ldin(fc2b, tid, bf);
        for (int k = 0; k < 32; ++k) a += z1[k] * ldin(fc2w, k * 10 + tid, bf);
        z2[tid] = a;
    }
    __syncthreads();
    if (tid == 0) {
        float mm = z2[0];
        for (int c = 1; c < 10; ++c) mm = fmaxf(mm, z2[c]);
        float ss = 0.f;
        for (int c = 0; c < 10; ++c) ss += expf(z2[c] - mm);
        slse = mm + logf(ss);
    }
    __syncthreads();
    if (tid < 10) stout(out, g * 10 + tid, z2[tid] - slse, bf);
}

// ---------------- launch ----------------

extern "C" void kernel_launch(void* const* d_in, const int* in_sizes, int n_in,
                              void* d_out, int out_size, void* d_ws, size_t ws_size,
                              hipStream_t stream) {
    const void* x     = d_in[0];
    const int*  ei    = (const int*)d_in[1];
    const int*  batch = (const int*)d_in[2];
    const int* srcp = ei;
    const int* dstp = ei + EE;
    const void* W[3]   = {d_in[3],  d_in[7],  d_in[11]};
    const void* gg_[3] = {d_in[5],  d_in[9],  d_in[13]};
    const void* be_[3] = {d_in[6],  d_in[10], d_in[14]};
    const void* fc1w = d_in[15];
    const void* fc1b = d_in[16];
    const void* fc2w = d_in[17];
    const void* fc2b = d_in[18];

    char* ws = (char*)d_ws;
    size_t off = 0;
    auto alloc = [&](size_t bytes) { size_t o = off; off = (off + bytes + 255) & ~(size_t)255; return o; };
    ushort* xws     = (ushort*)(ws + alloc((size_t)NN * HH * 2));
    ushort* hagg    = (ushort*)(ws + alloc((size_t)NN * HH * 2));
    uint*   ebuf    = (uint*)  (ws + alloc((size_t)NB_BUCKET * BCAP * 4));
    int*    csr     = (int*)   (ws + alloc(((size_t)NB_BUCKET * BCAP + 64) * 4));
    uint*   rowinfo = (uint*)  (ws + alloc((size_t)NN * 4));
    float*  dis     = (float*) (ws + alloc((size_t)NN * 4));
    uint4*  wpack   = (uint4*) (ws + alloc((size_t)3 * 512 * 16));
    size_t  zoff    = alloc((size_t)NB_BUCKET * 4);          // bcur (zeroed)
    int*    bcur    = (int*)(ws + zoff);
    float*  stats   = (float*) (ws + alloc((size_t)3 * NSLICE * 128 * 4));  // zeroed
    size_t  zend    = off;
    int*    dflag   = (int*)   (ws + alloc(256));
    if (off > ws_size) return;

    const int AB = NN / 8;            // 12500 blocks, 2 nodes per wave, 8 per block
    const int SL = NSLICE * 128;
    const int ZQ = (int)((zend - zoff) / 16);

    // prep: flag + zero(bcur,stats) + pack W0/W1/W2 into MFMA fragment layout
    k_prep<<<17, 256, 0, stream>>>((const uint*)x, W[0], W[1], W[2], dflag, wpack,
                                   (uint4*)(ws + zoff), ZQ);
    // edge bucket-scatter (512t, proven-fast config)
    k_bscatter<<<192, 512, 0, stream>>>(srcp, dstp, bcur, ebuf);
    // fused: bucket counting-sort  ||  layer-0 GEMM (both depend only on scatter)
    k_bg0<<<NB_BUCKET + GB, 256, 0, stream>>>(x, wpack, xws, dflag, ebuf, bcur,
                                              rowinfo, dis, csr);

    k_agg<1><<<AB, 256, 0, stream>>>(xws, rowinfo, csr, dis, hagg, stats);

    k_gemm1<<<GB, 256, 0, stream>>>(hagg, wpack + 512, stats, gg_[0], be_[0], dis, xws, dflag);
    k_agg<0><<<AB, 256, 0, stream>>>(xws, rowinfo, csr, dis, hagg, stats + SL);

    k_gemm1<<<GB, 256, 0, stream>>>(hagg, wpack + 1024, stats + SL, gg_[1], be_[1], dis, xws, dflag);
    k_agg<0><<<AB, 256, 0, stream>>>(xws, rowinfo, csr, dis, hagg, stats + 2 * SL);

    k_poolhead<<<GG, 256, 0, stream>>>(hagg, stats + 2 * SL, gg_[2], be_[2], batch,
                                       fc1w, fc1b, fc2w, fc2b, d_out, dflag);
}